// Round 1
// 418.028 us; speedup vs baseline: 1.0583x; 1.0583x over previous
//
#include <hip/hip_runtime.h>
#include <math.h>

#define DIMD    1024
#define MLPD    4096
#define DSTATE  16
#define DCONV   4
#define HALF    1024
#define DINNER  2048
#define DTRANK  64
#define BSZ     2
#define SEQ     2048
#define NTOK    (BSZ*SEQ)   // 4096
#define NCH     64
#define CL      (SEQ/NCH)   // 32

typedef short bf16x8 __attribute__((ext_vector_type(8)));
typedef float f32x4  __attribute__((ext_vector_type(4)));
typedef unsigned short u16;
typedef unsigned int   u32;
typedef unsigned short u16x4 __attribute__((ext_vector_type(4)));

__device__ __forceinline__ u16 f2bf(float x) {
    union { float f; unsigned int u; } v; v.f = x;
    unsigned int r = (v.u + 0x7FFFu + ((v.u >> 16) & 1u)) >> 16;
    return (u16)r;
}
__device__ __forceinline__ float bf2f(u16 x) {
    union { unsigned int u; float f; } v; v.u = ((unsigned int)x) << 16;
    return v.f;
}

// ---------------- fused LN1 + weight f32->bf16 convert -------------------
#define SZ_WIN  (DINNER*DIMD)
#define SZ_WXP  (96*HALF)
#define SZ_WDT  (HALF*DTRANK)
#define SZ_WOUT (DIMD*DINNER)
#define SZ_WM1  (MLPD*DIMD)
#define SZ_WM2  (DIMD*MLPD)
#define SZ_TOT  (SZ_WIN+SZ_WXP+SZ_WDT+SZ_WOUT+SZ_WM1+SZ_WM2)
// all segment sizes are multiples of 1024 -> 4 elems/thread, no straddling
#define CVT_BLOCKS (SZ_TOT / 1024)

__global__ __launch_bounds__(256) void cvtln_kernel(
        const float* __restrict__ x, const float* __restrict__ g,
        const float* __restrict__ b, u16* __restrict__ xn_bf,
        const float* __restrict__ s0, u16* __restrict__ d0,
        const float* __restrict__ s1, u16* __restrict__ d1,
        const float* __restrict__ s2, u16* __restrict__ d2,
        const float* __restrict__ s3, u16* __restrict__ d3,
        const float* __restrict__ s4, u16* __restrict__ d4,
        const float* __restrict__ s5, u16* __restrict__ d5) {
    if (blockIdx.x >= NTOK) {
        int i = (blockIdx.x - NTOK) * 1024 + threadIdx.x * 4;
        #define CVT4(s, d) { \
            float4 v = *(const float4*)((s) + i); \
            u16x4 o; o[0]=f2bf(v.x); o[1]=f2bf(v.y); o[2]=f2bf(v.z); o[3]=f2bf(v.w); \
            *(u16x4*)((d) + i) = o; }
        if (i < SZ_WIN)  { CVT4(s0, d0); return; }  i -= SZ_WIN;
        if (i < SZ_WXP)  { CVT4(s1, d1); return; }  i -= SZ_WXP;
        if (i < SZ_WDT)  { CVT4(s2, d2); return; }  i -= SZ_WDT;
        if (i < SZ_WOUT) { CVT4(s3, d3); return; }  i -= SZ_WOUT;
        if (i < SZ_WM1)  { CVT4(s4, d4); return; }  i -= SZ_WM1;
        if (i < SZ_WM2)  { CVT4(s5, d5); }
        #undef CVT4
        return;
    }
    __shared__ float sm[4];
    int row = blockIdx.x;
    int t = threadIdx.x;
    const float4* xr = (const float4*)(x + (size_t)row * DIMD);
    float4 v = xr[t];
    float s = v.x + v.y + v.z + v.w;
    for (int off = 32; off > 0; off >>= 1) s += __shfl_down(s, off, 64);
    if ((t & 63) == 0) sm[t >> 6] = s;
    __syncthreads();
    float mu = (sm[0] + sm[1] + sm[2] + sm[3]) * (1.0f / DIMD);
    float dx = v.x - mu, dy = v.y - mu, dz = v.z - mu, dw = v.w - mu;
    float ss = dx*dx + dy*dy + dz*dz + dw*dw;
    for (int off = 32; off > 0; off >>= 1) ss += __shfl_down(ss, off, 64);
    __syncthreads();
    if ((t & 63) == 0) sm[t >> 6] = ss;
    __syncthreads();
    float var = (sm[0] + sm[1] + sm[2] + sm[3]) * (1.0f / DIMD);
    float rs = rsqrtf(var + 1e-5f);
    float4 gv = ((const float4*)g)[t];
    float4 bv = ((const float4*)b)[t];
    u16* o = xn_bf + (size_t)row * DIMD + t * 4;
    o[0] = f2bf(dx * rs * gv.x + bv.x);
    o[1] = f2bf(dy * rs * gv.y + bv.y);
    o[2] = f2bf(dz * rs * gv.z + bv.z);
    o[3] = f2bf(dw * rs * gv.w + bv.w);
}

// ---------------- x_proj GEMM: 4 waves = 2 m-tiles x 2 K-halves ----------
__global__ __launch_bounds__(256) void gemm_small_kernel(
        const u16* __restrict__ A, int lda,
        const u16* __restrict__ W, int K, int N,
        float* __restrict__ Cf, u16* __restrict__ Cb) {
    __shared__ f32x4 red[2][64];
    int t = threadIdx.x;
    int w = t >> 6, lane = t & 63;
    int mt = w & 1, kh = w >> 1;
    int m0 = blockIdx.x * 32 + mt * 16;
    int n0 = blockIdx.y * 16;
    int r = lane & 15, quad = lane >> 4;
    int Kh = K >> 1;
    f32x4 acc = {0.f, 0.f, 0.f, 0.f};
    const u16* ap = A + (size_t)(m0 + r) * lda + kh * Kh + quad * 8;
    const u16* wp = W + (size_t)(n0 + r) * K   + kh * Kh + quad * 8;
    for (int k = 0; k < Kh; k += 32) {
        bf16x8 av = *(const bf16x8*)(ap + k);
        bf16x8 bv = *(const bf16x8*)(wp + k);
        acc = __builtin_amdgcn_mfma_f32_16x16x32_bf16(av, bv, acc, 0, 0, 0);
    }
    if (kh == 1) red[mt][lane] = acc;
    __syncthreads();
    if (kh == 0) {
        f32x4 o = red[mt][lane];
        int col = n0 + r;
        #pragma unroll
        for (int i = 0; i < 4; ++i) {
            int row = m0 + quad * 4 + i;
            size_t idx = (size_t)row * N + col;
            float v = acc[i] + o[i];
            Cf[idx] = v;
            Cb[idx] = f2bf(v);
        }
    }
}

// ---------------- big GEMM: 128xTN tile, BK=32, dbuf, hoisted addrs ------
// EPI: 0 f32 | 1 bias+softplus f32 | 2 bias+gelu(tanh) bf16 | 3 +resid f32
//      4 bias+resid f32 | 5 plain bf16
template<int EPI, int TN, int KS>
__global__ __launch_bounds__(256) void gemm128_kernel(
        const u16* __restrict__ A, int lda, const u16* __restrict__ W,
        int K, int N,
        const float* __restrict__ bias, const float* __restrict__ resid,
        float* __restrict__ Cf, float* __restrict__ Cf2,
        u16* __restrict__ Cb) {
    constexpr int NF = TN / 32;
    __shared__ u16 As0[128 * 32], As1[128 * 32];
    __shared__ u16 Bs0[TN * 32],  Bs1[TN * 32];
    const int t = threadIdx.x;
    const int w = t >> 6;
    const int lane = t & 63;
    const int r = lane & 15, quad = lane >> 4;
    const int wm = w & 1, wn = w >> 1;
    const int m0 = blockIdx.x * 128;
    const int n0 = blockIdx.y * TN;
    const int Kloc = K / KS;
    const int kz = (KS == 2) ? blockIdx.z : 0;

    f32x4 acc[4][NF];
    #pragma unroll
    for (int mi = 0; mi < 4; ++mi)
        #pragma unroll
        for (int ni = 0; ni < NF; ++ni)
            acc[mi][ni] = (f32x4){0.f, 0.f, 0.f, 0.f};

    const u16* pa[2];
    const u16* pb[NF / 2];
    #pragma unroll
    for (int i = 0; i < 2; ++i) {
        int c = (i * 4 + w) * 64 + lane;
        int row = c >> 2;
        int q = (c & 3) ^ ((row >> 1) & 3);
        pa[i] = A + (size_t)(m0 + row) * lda + (size_t)kz * Kloc + q * 8;
    }
    #pragma unroll
    for (int i = 0; i < NF / 2; ++i) {
        int c = (i * 4 + w) * 64 + lane;
        int row = c >> 2;
        int q = (c & 3) ^ ((row >> 1) & 3);
        pb[i] = W + (size_t)(n0 + row) * K + (size_t)kz * Kloc + q * 8;
    }
    const int qs = quad ^ ((r >> 1) & 3);
    int aoff[4], boff[NF];
    #pragma unroll
    for (int mi = 0; mi < 4; ++mi)
        aoff[mi] = (wm * 64 + mi * 16 + r) * 32 + qs * 8;
    #pragma unroll
    for (int ni = 0; ni < NF; ++ni)
        boff[ni] = (wn * (TN / 2) + ni * 16 + r) * 32 + qs * 8;

    auto stage = [&](u16* __restrict__ Ad, u16* __restrict__ Bd) {
        #pragma unroll
        for (int i = 0; i < 2; ++i) {
            __builtin_amdgcn_global_load_lds(
                (const __attribute__((address_space(1))) u32*)pa[i],
                (__attribute__((address_space(3))) u32*)(Ad + (i * 4 + w) * 512),
                16, 0, 0);
            pa[i] += 32;
        }
        #pragma unroll
        for (int i = 0; i < NF / 2; ++i) {
            __builtin_amdgcn_global_load_lds(
                (const __attribute__((address_space(1))) u32*)pb[i],
                (__attribute__((address_space(3))) u32*)(Bd + (i * 4 + w) * 512),
                16, 0, 0);
            pb[i] += 32;
        }
    };
    auto compute = [&](const u16* __restrict__ Ab, const u16* __restrict__ Bb) {
        bf16x8 af[4], bfr[NF];
        #pragma unroll
        for (int mi = 0; mi < 4; ++mi) af[mi] = *(const bf16x8*)(Ab + aoff[mi]);
        #pragma unroll
        for (int ni = 0; ni < NF; ++ni) bfr[ni] = *(const bf16x8*)(Bb + boff[ni]);
        #pragma unroll
        for (int mi = 0; mi < 4; ++mi)
            #pragma unroll
            for (int ni = 0; ni < NF; ++ni)
                acc[mi][ni] = __builtin_amdgcn_mfma_f32_16x16x32_bf16(
                    af[mi], bfr[ni], acc[mi][ni], 0, 0, 0);
    };

    stage(As0, Bs0);
    for (int k0 = 0; k0 < Kloc; k0 += 64) {
        __syncthreads();
        if (k0 + 32 < Kloc) stage(As1, Bs1);
        compute(As0, Bs0);
        __syncthreads();
        if (k0 + 64 < Kloc) stage(As0, Bs0);
        compute(As1, Bs1);
    }

    float* Cfo = (KS == 2 && kz) ? Cf2 : Cf;
    #pragma unroll
    for (int mi = 0; mi < 4; ++mi) {
        #pragma unroll
        for (int i = 0; i < 4; ++i) {
            int row = m0 + wm * 64 + mi * 16 + quad * 4 + i;
            #pragma unroll
            for (int ni = 0; ni < NF; ++ni) {
                int col = n0 + wn * (TN / 2) + ni * 16 + r;
                size_t idx = (size_t)row * N + col;
                float v = acc[mi][ni][i];
                if (EPI == 1) { v += bias[col]; v = (v > 20.f) ? v : log1pf(expf(v)); }
                if (EPI == 2) {
                    v += bias[col];
                    // gelu, tanh form: v * e/(e+1), e = exp(2*0.7978845608*(v+0.044715 v^3))
                    float e = __expf(fminf(1.5957691216f * v + 0.0713548162f * v * v * v, 80.f));
                    v = v * __fdividef(e, e + 1.f);
                }
                if (EPI == 3) { v += resid[idx]; }
                if (EPI == 4) { v += bias[col] + resid[idx]; }
                if (EPI == 2 || EPI == 5) Cb[idx] = f2bf(v);
                else                      Cfo[idx] = v;
            }
        }
    }
}

// ---------------- split-K reduce: out = P0 + P1 + bias + resid -----------
__global__ __launch_bounds__(256) void reduce2_kernel(
        const float* __restrict__ P0, const float* __restrict__ P1,
        const float* __restrict__ bias, const float* __restrict__ resid,
        float* __restrict__ out) {
    size_t idx = ((size_t)blockIdx.x * 256 + threadIdx.x) * 4;
    float4 a = *(const float4*)(P0 + idx);
    float4 b = *(const float4*)(P1 + idx);
    float4 rr = *(const float4*)(resid + idx);
    int col = (int)(idx & (DIMD - 1));
    float4 bb = *(const float4*)(bias + col);
    float4 o;
    o.x = a.x + b.x + rr.x + bb.x;
    o.y = a.y + b.y + rr.y + bb.y;
    o.z = a.z + b.z + rr.z + bb.z;
    o.w = a.w + b.w + rr.w + bb.w;
    *(float4*)(out + idx) = o;
}

// ---------------- fused out_proj reduce + residual + LN2 -----------------
// x2 = P0 + P1 + resid ; ln2_bf = LN(x2)*g + b   (block per row)
__global__ __launch_bounds__(256) void reduce_ln_kernel(
        const float* __restrict__ P0, const float* __restrict__ P1,
        const float* __restrict__ resid,
        const float* __restrict__ g, const float* __restrict__ b,
        float* __restrict__ x2, u16* __restrict__ out_bf) {
    __shared__ float sm[4];
    int row = blockIdx.x;
    int t = threadIdx.x;
    size_t base = (size_t)row * DIMD + t * 4;
    float4 a  = *(const float4*)(P0 + base);
    float4 p  = *(const float4*)(P1 + base);
    float4 rr = *(const float4*)(resid + base);
    float4 v;
    v.x = a.x + p.x + rr.x;
    v.y = a.y + p.y + rr.y;
    v.z = a.z + p.z + rr.z;
    v.w = a.w + p.w + rr.w;
    *(float4*)(x2 + base) = v;
    float s = v.x + v.y + v.z + v.w;
    for (int off = 32; off > 0; off >>= 1) s += __shfl_down(s, off, 64);
    if ((t & 63) == 0) sm[t >> 6] = s;
    __syncthreads();
    float mu = (sm[0] + sm[1] + sm[2] + sm[3]) * (1.0f / DIMD);
    float dx = v.x - mu, dy = v.y - mu, dz = v.z - mu, dw = v.w - mu;
    float ss = dx*dx + dy*dy + dz*dz + dw*dw;
    for (int off = 32; off > 0; off >>= 1) ss += __shfl_down(ss, off, 64);
    __syncthreads();
    if ((t & 63) == 0) sm[t >> 6] = ss;
    __syncthreads();
    float var = (sm[0] + sm[1] + sm[2] + sm[3]) * (1.0f / DIMD);
    float rs = rsqrtf(var + 1e-5f);
    float4 gv = ((const float4*)g)[t];
    float4 bv = ((const float4*)b)[t];
    u16* o = out_bf + base;
    o[0] = f2bf(dx * rs * gv.x + bv.x);
    o[1] = f2bf(dy * rs * gv.y + bv.y);
    o[2] = f2bf(dz * rs * gv.z + bv.z);
    o[3] = f2bf(dw * rs * gv.w + bv.w);
}

// ---------------- depthwise conv + SiLU, sliding window (8 l / thread) ---
__global__ __launch_bounds__(256) void conv_silu_kernel(
        const u16* __restrict__ xz,
        const float* __restrict__ wx, const float* __restrict__ bx,
        const float* __restrict__ wz, const float* __restrict__ bz,
        u16* __restrict__ u_bf, u16* __restrict__ ycat) {
    int c  = blockIdx.x * 256 + threadIdx.x;   // 0..1023
    int gy = blockIdx.y;                       // 0..NTOK/8-1
    int b  = gy >> 8;                          // SEQ/8 = 256 chunks per batch
    int l0 = (gy & 255) * 8;
    const u16* base = xz + ((size_t)(b * SEQ + l0)) * DINNER;
    float wxr[4], wzr[4];
    #pragma unroll
    for (int k = 0; k < 4; ++k) { wxr[k] = wx[c * 4 + k]; wzr[k] = wz[c * 4 + k]; }
    float bxv = bx[c], bzv = bz[c];
    // window: rows l-1, l, l+1 (x and z halves)
    float xm1 = (l0 > 0) ? bf2f(base[c - DINNER]) : 0.f;
    float x0v = bf2f(base[c]);
    float x1v = bf2f(base[c + DINNER]);
    float zm1 = (l0 > 0) ? bf2f(base[HALF + c - DINNER]) : 0.f;
    float z0v = bf2f(base[HALF + c]);
    float z1v = bf2f(base[HALF + c + DINNER]);
    u16* up = u_bf + ((size_t)(b * SEQ + l0)) * HALF + c;
    u16* yp = ycat + ((size_t)(b * SEQ + l0)) * DINNER + HALF + c;
    #pragma unroll
    for (int l = 0; l < 8; ++l) {
        bool in = (l0 + l + 2) < SEQ;
        float x2v = in ? bf2f(base[(size_t)(l + 2) * DINNER + c]) : 0.f;
        float z2v = in ? bf2f(base[(size_t)(l + 2) * DINNER + HALF + c]) : 0.f;
        float ax = bxv + wxr[0]*xm1 + wxr[1]*x0v + wxr[2]*x1v + wxr[3]*x2v;
        float az = bzv + wzr[0]*zm1 + wzr[1]*z0v + wzr[2]*z1v + wzr[3]*z2v;
        float sx = ax * __fdividef(1.f, 1.f + __expf(-ax));
        float sz = az * __fdividef(1.f, 1.f + __expf(-az));
        *up = f2bf(sx); *yp = f2bf(sz);
        up += HALF; yp += DINNER;
        xm1 = x0v; x0v = x1v; x1v = x2v;
        zm1 = z0v; z0v = z1v; z1v = z2v;
    }
}

// ---------------- chunk-parallel selective scan (thread per chain) -------
__global__ __launch_bounds__(256) void scan_p1_kernel(
        const float* __restrict__ delta, const u16* __restrict__ u_bf,
        const float* __restrict__ x_dbl, const float* __restrict__ A_log,
        float* __restrict__ hfin, float* __restrict__ dsum) {
    int t  = blockIdx.x * 256 + threadIdx.x;
    int d  = t & (HALF - 1);
    int ch = (t >> 10) & (NCH - 1);
    int b  = t >> 16;
    float Ac[16], h[16];
    #pragma unroll
    for (int i = 0; i < 4; ++i) {
        float4 a = *(const float4*)&A_log[d * DSTATE + i * 4];
        Ac[4*i+0] = -__expf(a.x); Ac[4*i+1] = -__expf(a.y);
        Ac[4*i+2] = -__expf(a.z); Ac[4*i+3] = -__expf(a.w);
        h[4*i+0] = 0.f; h[4*i+1] = 0.f; h[4*i+2] = 0.f; h[4*i+3] = 0.f;
    }
    int l0 = b * SEQ + ch * CL;
    size_t off = (size_t)l0 * HALF + d;
    const float* xrow = x_dbl + (size_t)l0 * 96;
    float ds = 0.f;
    #pragma unroll 4
    for (int l = 0; l < CL; ++l) {
        float dl = delta[off];
        float uv = bf2f(u_bf[off]);
        off += HALF;
        float4 B0 = *(const float4*)(xrow + 64);
        float4 B1 = *(const float4*)(xrow + 68);
        float4 B2 = *(const float4*)(xrow + 72);
        float4 B3 = *(const float4*)(xrow + 76);
        xrow += 96;
        float dBu = dl * uv;
        ds += dl;
        float Bv[16] = {B0.x,B0.y,B0.z,B0.w, B1.x,B1.y,B1.z,B1.w,
                        B2.x,B2.y,B2.z,B2.w, B3.x,B3.y,B3.z,B3.w};
        #pragma unroll
        for (int n = 0; n < 16; ++n)
            h[n] = __expf(dl * Ac[n]) * h[n] + dBu * Bv[n];
    }
    float4* hf = (float4*)&hfin[(size_t)t * 16];
    #pragma unroll
    for (int i = 0; i < 4; ++i)
        hf[i] = (float4){h[4*i+0], h[4*i+1], h[4*i+2], h[4*i+3]};
    dsum[t] = ds;
}

__global__ __launch_bounds__(256) void scan_p2_kernel(
        const float* __restrict__ A_log, const float* __restrict__ dsum,
        const float* __restrict__ hfin, float* __restrict__ hin) {
    int t = blockIdx.x * 256 + threadIdx.x;
    int n = t & 15;
    int d = (t >> 4) & (HALF - 1);
    int b = t >> 14;
    float Ac = -__expf(A_log[d * DSTATE + n]);
    float h = 0.f;
    for (int ch = 0; ch < NCH; ++ch) {
        size_t chain = ((size_t)(b * NCH + ch) * HALF) + d;
        hin[chain * 16 + n] = h;
        float ds = dsum[chain];
        h = __expf(Ac * ds) * h + hfin[chain * 16 + n];
    }
}

__global__ __launch_bounds__(256) void scan_p3_kernel(
        const float* __restrict__ delta, const u16* __restrict__ u_bf,
        const float* __restrict__ x_dbl, const float* __restrict__ A_log,
        const float* __restrict__ Dp, const float* __restrict__ hin,
        u16* __restrict__ ycat) {
    int t  = blockIdx.x * 256 + threadIdx.x;
    int d  = t & (HALF - 1);
    int ch = (t >> 10) & (NCH - 1);
    int b  = t >> 16;
    float Ac[16], h[16];
    #pragma unroll
    for (int i = 0; i < 4; ++i) {
        float4 a  = *(const float4*)&A_log[d * DSTATE + i * 4];
        float4 hv = *(const float4*)&hin[(size_t)t * 16 + i * 4];
        Ac[4*i+0] = -__expf(a.x); Ac[4*i+1] = -__expf(a.y);
        Ac[4*i+2] = -__expf(a.z); Ac[4*i+3] = -__expf(a.w);
        h[4*i+0] = hv.x; h[4*i+1] = hv.y; h[4*i+2] = hv.z; h[4*i+3] = hv.w;
    }
    float Dv = Dp[d];
    int l0 = b * SEQ + ch * CL;
    size_t off = (size_t)l0 * HALF + d;
    const float* xrow = x_dbl + (size_t)l0 * 96;
    u16* yp = ycat + (size_t)l0 * DINNER + d;
    #pragma unroll 4
    for (int l = 0; l < CL; ++l) {
        float dl = delta[off];
        float uv = bf2f(u_bf[off]);
        off += HALF;
        float4 B0 = *(const float4*)(xrow + 64);
        float4 B1 = *(const float4*)(xrow + 68);
        float4 B2 = *(const float4*)(xrow + 72);
        float4 B3 = *(const float4*)(xrow + 76);
        float4 C0 = *(const float4*)(xrow + 80);
        float4 C1 = *(const float4*)(xrow + 84);
        float4 C2 = *(const float4*)(xrow + 88);
        float4 C3 = *(const float4*)(xrow + 92);
        xrow += 96;
        float dBu = dl * uv;
        float Bv[16] = {B0.x,B0.y,B0.z,B0.w, B1.x,B1.y,B1.z,B1.w,
                        B2.x,B2.y,B2.z,B2.w, B3.x,B3.y,B3.z,B3.w};
        float Cv[16] = {C0.x,C0.y,C0.z,C0.w, C1.x,C1.y,C1.z,C1.w,
                        C2.x,C2.y,C2.z,C2.w, C3.x,C3.y,C3.z,C3.w};
        float y = uv * Dv;
        #pragma unroll
        for (int n = 0; n < 16; ++n) {
            h[n] = __expf(dl * Ac[n]) * h[n] + dBu * Bv[n];
            y += h[n] * Cv[n];
        }
        *yp = f2bf(y);
        yp += DINNER;
    }
}

// ---------------- host-side orchestration ----------------
extern "C" void kernel_launch(void* const* d_in, const int* in_sizes, int n_in,
                              void* d_out, int out_size, void* d_ws, size_t ws_size,
                              hipStream_t stream) {
    const float* x         = (const float*)d_in[0];
    const float* ln1_g     = (const float*)d_in[1];
    const float* ln1_b     = (const float*)d_in[2];
    const float* in_proj_w = (const float*)d_in[3];
    const float* conv_x_w  = (const float*)d_in[4];
    const float* conv_x_b  = (const float*)d_in[5];
    const float* conv_z_w  = (const float*)d_in[6];
    const float* conv_z_b  = (const float*)d_in[7];
    const float* x_proj_w  = (const float*)d_in[8];
    const float* dt_proj_w = (const float*)d_in[9];
    const float* dt_proj_b = (const float*)d_in[10];
    const float* A_log     = (const float*)d_in[11];
    const float* Dp        = (const float*)d_in[12];
    const float* out_proj_w= (const float*)d_in[13];
    const float* ln2_g     = (const float*)d_in[14];
    const float* ln2_b     = (const float*)d_in[15];
    const float* mlp_w1    = (const float*)d_in[16];
    const float* mlp_b1    = (const float*)d_in[17];
    const float* mlp_w2    = (const float*)d_in[18];
    const float* mlp_b2    = (const float*)d_in[19];
    float* out = (float*)d_out;

    char* p = (char*)d_ws;
    auto alloc = [&](size_t bytes) {
        char* r = p; p += (bytes + 255) & ~(size_t)255; return r;
    };
    u16*   w_in   = (u16*)  alloc((size_t)DINNER * DIMD * 2);
    u16*   w_xp   = (u16*)  alloc((size_t)96 * HALF * 2);
    u16*   w_dt   = (u16*)  alloc((size_t)HALF * DTRANK * 2);
    u16*   w_out  = (u16*)  alloc((size_t)DIMD * DINNER * 2);
    u16*   w_m1   = (u16*)  alloc((size_t)MLPD * DIMD * 2);
    u16*   w_m2   = (u16*)  alloc((size_t)DIMD * MLPD * 2);
    u16*   xn_bf  = (u16*)  alloc((size_t)NTOK * DIMD * 2);
    u16*   xz_bf  = (u16*)  alloc((size_t)NTOK * DINNER * 2);  // 16 MB
    u16*   u_bf   = (u16*)  alloc((size_t)NTOK * HALF * 2);
    u16*   ycat   = (u16*)  alloc((size_t)NTOK * DINNER * 2);
    float* x_dbl  = (float*)alloc((size_t)NTOK * 96 * 4);
    u16*   xdbl_bf= (u16*)  alloc((size_t)NTOK * 96 * 2);
    float* delta  = (float*)alloc((size_t)NTOK * HALF * 4);    // 16 MB
    float* x2     = (float*)alloc((size_t)NTOK * DIMD * 4);
    u16*   ln2_bf = (u16*)  alloc((size_t)NTOK * DIMD * 2);
    u16*   mlp_h  = (u16*)  alloc((size_t)NTOK * MLPD * 2);    // 32 MB
    // scan scratch aliases mlp_h (dead until mlp1):
    float* hfin = (float*)mlp_h;
    float* hin  = hfin + (size_t)BSZ * NCH * HALF * DSTATE;
    float* dsum = hin  + (size_t)BSZ * NCH * HALF * DSTATE;
    // split-K partials alias delta (dead after scan) and xz_bf (dead after conv):
    float* P0 = delta;
    float* P1 = (float*)xz_bf;

    // fused LN1 + weight conversions (weights: 4 elems/thread, float4 in, u16x4 out)
    cvtln_kernel<<<NTOK + CVT_BLOCKS, 256, 0, stream>>>(
        x, ln1_g, ln1_b, xn_bf,
        in_proj_w, w_in, x_proj_w, w_xp, dt_proj_w, w_dt,
        out_proj_w, w_out, mlp_w1, w_m1, mlp_w2, w_m2);

    // in_proj: xz_bf[4096,2048] = xn @ W^T (bf16 out, 128x128 tile -> 512 blocks)
    gemm128_kernel<5,128,1><<<dim3(NTOK/128, DINNER/128), 256, 0, stream>>>(
        xn_bf, DIMD, w_in, DIMD, DINNER, nullptr, nullptr, nullptr, nullptr, xz_bf);

    // depthwise conv + silu (sliding window)
    conv_silu_kernel<<<dim3(HALF/256, NTOK/8), 256, 0, stream>>>(
        xz_bf, conv_x_w, conv_x_b, conv_z_w, conv_z_b, u_bf, ycat);

    // x_proj: [4096,96] = u @ W^T  (split-K in block)
    gemm_small_kernel<<<dim3(NTOK/32, 96/16), 256, 0, stream>>>(
        u_bf, HALF, w_xp, HALF, 96, x_dbl, xdbl_bf);

    // dt_proj: delta = softplus(dt @ W^T + b)
    gemm128_kernel<1,64,1><<<dim3(NTOK/128, HALF/64), 256, 0, stream>>>(
        xdbl_bf, 96, w_dt, DTRANK, HALF, dt_proj_b, nullptr, delta, nullptr, nullptr);

    // chunk-parallel scan
    scan_p1_kernel<<<(BSZ*NCH*HALF)/256, 256, 0, stream>>>(
        delta, u_bf, x_dbl, A_log, hfin, dsum);
    scan_p2_kernel<<<(BSZ*HALF*DSTATE)/256, 256, 0, stream>>>(
        A_log, dsum, hfin, hin);
    scan_p3_kernel<<<(BSZ*NCH*HALF)/256, 256, 0, stream>>>(
        delta, u_bf, x_dbl, A_log, Dp, hin, ycat);

    // out_proj split-K=2, 128x128 tile: P = ycat @ W^T (512 blocks = 2/CU)
    gemm128_kernel<0,128,2><<<dim3(NTOK/128, DIMD/128, 2), 256, 0, stream>>>(
        ycat, DINNER, w_out, DINNER, DIMD, nullptr, nullptr, P0, P1, nullptr);
    // fused: x2 = P0+P1+x ; ln2_bf = LN(x2)
    reduce_ln_kernel<<<NTOK, 256, 0, stream>>>(
        P0, P1, x, ln2_g, ln2_b, x2, ln2_bf);

    // MLP1: gelu(ln2 @ W1^T + b1) -> bf16 (overwrites scan scratch - ok)
    gemm128_kernel<2,128,1><<<dim3(NTOK/128, MLPD/128), 256, 0, stream>>>(
        ln2_bf, DIMD, w_m1, DIMD, MLPD, mlp_b1, nullptr, nullptr, nullptr, mlp_h);

    // MLP2 split-K=2, 128x128 tile: P = mlp_h @ W2^T ; out = P0+P1+b2+x2
    gemm128_kernel<0,128,2><<<dim3(NTOK/128, DIMD/128, 2), 256, 0, stream>>>(
        mlp_h, MLPD, w_m2, MLPD, DIMD, nullptr, nullptr, P0, P1, nullptr);
    reduce2_kernel<<<(NTOK*DIMD)/1024, 256, 0, stream>>>(
        P0, P1, mlp_b2, x2, out);
}

// Round 2
// 412.960 us; speedup vs baseline: 1.0713x; 1.0123x over previous
//
#include <hip/hip_runtime.h>
#include <math.h>

#define DIMD    1024
#define MLPD    4096
#define DSTATE  16
#define DCONV   4
#define HALF    1024
#define DINNER  2048
#define DTRANK  64
#define BSZ     2
#define SEQ     2048
#define NTOK    (BSZ*SEQ)   // 4096
#define NCH     64
#define CL      (SEQ/NCH)   // 32

typedef short bf16x8 __attribute__((ext_vector_type(8)));
typedef float f32x4  __attribute__((ext_vector_type(4)));
typedef float f32x16 __attribute__((ext_vector_type(16)));
typedef unsigned short u16;
typedef unsigned int   u32;
typedef unsigned short u16x4 __attribute__((ext_vector_type(4)));

__device__ __forceinline__ u16 f2bf(float x) {
    union { float f; unsigned int u; } v; v.f = x;
    unsigned int r = (v.u + 0x7FFFu + ((v.u >> 16) & 1u)) >> 16;
    return (u16)r;
}
__device__ __forceinline__ float bf2f(u16 x) {
    union { unsigned int u; float f; } v; v.u = ((unsigned int)x) << 16;
    return v.f;
}

// ---------------- fused LN1 + weight f32->bf16 convert -------------------
#define SZ_WIN  (DINNER*DIMD)
#define SZ_WXP  (96*HALF)
#define SZ_WDT  (HALF*DTRANK)
#define SZ_WOUT (DIMD*DINNER)
#define SZ_WM1  (MLPD*DIMD)
#define SZ_WM2  (DIMD*MLPD)
#define SZ_TOT  (SZ_WIN+SZ_WXP+SZ_WDT+SZ_WOUT+SZ_WM1+SZ_WM2)
// all segment sizes are multiples of 1024 -> 4 elems/thread, no straddling
#define CVT_BLOCKS (SZ_TOT / 1024)

__global__ __launch_bounds__(256) void cvtln_kernel(
        const float* __restrict__ x, const float* __restrict__ g,
        const float* __restrict__ b, u16* __restrict__ xn_bf,
        const float* __restrict__ s0, u16* __restrict__ d0,
        const float* __restrict__ s1, u16* __restrict__ d1,
        const float* __restrict__ s2, u16* __restrict__ d2,
        const float* __restrict__ s3, u16* __restrict__ d3,
        const float* __restrict__ s4, u16* __restrict__ d4,
        const float* __restrict__ s5, u16* __restrict__ d5) {
    if (blockIdx.x >= NTOK) {
        int i = (blockIdx.x - NTOK) * 1024 + threadIdx.x * 4;
        #define CVT4(s, d) { \
            float4 v = *(const float4*)((s) + i); \
            u16x4 o; o[0]=f2bf(v.x); o[1]=f2bf(v.y); o[2]=f2bf(v.z); o[3]=f2bf(v.w); \
            *(u16x4*)((d) + i) = o; }
        if (i < SZ_WIN)  { CVT4(s0, d0); return; }  i -= SZ_WIN;
        if (i < SZ_WXP)  { CVT4(s1, d1); return; }  i -= SZ_WXP;
        if (i < SZ_WDT)  { CVT4(s2, d2); return; }  i -= SZ_WDT;
        if (i < SZ_WOUT) { CVT4(s3, d3); return; }  i -= SZ_WOUT;
        if (i < SZ_WM1)  { CVT4(s4, d4); return; }  i -= SZ_WM1;
        if (i < SZ_WM2)  { CVT4(s5, d5); }
        #undef CVT4
        return;
    }
    __shared__ float sm[4];
    int row = blockIdx.x;
    int t = threadIdx.x;
    const float4* xr = (const float4*)(x + (size_t)row * DIMD);
    float4 v = xr[t];
    float s = v.x + v.y + v.z + v.w;
    for (int off = 32; off > 0; off >>= 1) s += __shfl_down(s, off, 64);
    if ((t & 63) == 0) sm[t >> 6] = s;
    __syncthreads();
    float mu = (sm[0] + sm[1] + sm[2] + sm[3]) * (1.0f / DIMD);
    float dx = v.x - mu, dy = v.y - mu, dz = v.z - mu, dw = v.w - mu;
    float ss = dx*dx + dy*dy + dz*dz + dw*dw;
    for (int off = 32; off > 0; off >>= 1) ss += __shfl_down(ss, off, 64);
    __syncthreads();
    if ((t & 63) == 0) sm[t >> 6] = ss;
    __syncthreads();
    float var = (sm[0] + sm[1] + sm[2] + sm[3]) * (1.0f / DIMD);
    float rs = rsqrtf(var + 1e-5f);
    float4 gv = ((const float4*)g)[t];
    float4 bv = ((const float4*)b)[t];
    u16* o = xn_bf + (size_t)row * DIMD + t * 4;
    o[0] = f2bf(dx * rs * gv.x + bv.x);
    o[1] = f2bf(dy * rs * gv.y + bv.y);
    o[2] = f2bf(dz * rs * gv.z + bv.z);
    o[3] = f2bf(dw * rs * gv.w + bv.w);
}

// ---------------- x_proj GEMM: 4 waves = 2 m-tiles x 2 K-halves ----------
__global__ __launch_bounds__(256) void gemm_small_kernel(
        const u16* __restrict__ A, int lda,
        const u16* __restrict__ W, int K, int N,
        float* __restrict__ Cf, u16* __restrict__ Cb) {
    __shared__ f32x4 red[2][64];
    int t = threadIdx.x;
    int w = t >> 6, lane = t & 63;
    int mt = w & 1, kh = w >> 1;
    int m0 = blockIdx.x * 32 + mt * 16;
    int n0 = blockIdx.y * 16;
    int r = lane & 15, quad = lane >> 4;
    int Kh = K >> 1;
    f32x4 acc = {0.f, 0.f, 0.f, 0.f};
    const u16* ap = A + (size_t)(m0 + r) * lda + kh * Kh + quad * 8;
    const u16* wp = W + (size_t)(n0 + r) * K   + kh * Kh + quad * 8;
    for (int k = 0; k < Kh; k += 32) {
        bf16x8 av = *(const bf16x8*)(ap + k);
        bf16x8 bv = *(const bf16x8*)(wp + k);
        acc = __builtin_amdgcn_mfma_f32_16x16x32_bf16(av, bv, acc, 0, 0, 0);
    }
    if (kh == 1) red[mt][lane] = acc;
    __syncthreads();
    if (kh == 0) {
        f32x4 o = red[mt][lane];
        int col = n0 + r;
        #pragma unroll
        for (int i = 0; i < 4; ++i) {
            int row = m0 + quad * 4 + i;
            size_t idx = (size_t)row * N + col;
            float v = acc[i] + o[i];
            Cf[idx] = v;
            Cb[idx] = f2bf(v);
        }
    }
}

// ---------------- big GEMM: 128xTN tile, BK=32, dbuf, 32x32x16 MFMA ------
// EPI: 0 f32 | 1 bias+softplus f32 | 2 bias+gelu(tanh) bf16 | 3 +resid f32
//      4 bias+resid f32 | 5 plain bf16
// Per-wave 64x(TN/2) output as 2x(TN/64) fragments of 32x32.
template<int EPI, int TN, int KS>
__global__ __launch_bounds__(256) void gemm128_kernel(
        const u16* __restrict__ A, int lda, const u16* __restrict__ W,
        int K, int N,
        const float* __restrict__ bias, const float* __restrict__ resid,
        float* __restrict__ Cf, float* __restrict__ Cf2,
        u16* __restrict__ Cb) {
    constexpr int NF = TN / 32;      // B staging granule count (unchanged)
    constexpr int NN = TN / 64;      // 32x32 frags per wave in n
    __shared__ u16 As0[128 * 32], As1[128 * 32];
    __shared__ u16 Bs0[TN * 32],  Bs1[TN * 32];
    const int t = threadIdx.x;
    const int w = t >> 6;
    const int lane = t & 63;
    const int r32 = lane & 31;       // fragment row (A) / col (B)
    const int kh  = lane >> 5;       // k-half within a 16-wide K chunk
    const int wm = w & 1, wn = w >> 1;
    const int m0 = blockIdx.x * 128;
    const int n0 = blockIdx.y * TN;
    const int Kloc = K / KS;
    const int kz = (KS == 2) ? blockIdx.z : 0;

    f32x16 acc[2][NN];
    #pragma unroll
    for (int mi = 0; mi < 2; ++mi)
        #pragma unroll
        for (int ni = 0; ni < NN; ++ni)
            acc[mi][ni] = (f32x16){0.f,0.f,0.f,0.f,0.f,0.f,0.f,0.f,
                                   0.f,0.f,0.f,0.f,0.f,0.f,0.f,0.f};

    const u16* pa[2];
    const u16* pb[NF / 2];
    #pragma unroll
    for (int i = 0; i < 2; ++i) {
        int c = (i * 4 + w) * 64 + lane;
        int row = c >> 2;
        int q = (c & 3) ^ ((row >> 1) & 3);
        pa[i] = A + (size_t)(m0 + row) * lda + (size_t)kz * Kloc + q * 8;
    }
    #pragma unroll
    for (int i = 0; i < NF / 2; ++i) {
        int c = (i * 4 + w) * 64 + lane;
        int row = c >> 2;
        int q = (c & 3) ^ ((row >> 1) & 3);
        pb[i] = W + (size_t)(n0 + row) * K + (size_t)kz * Kloc + q * 8;
    }
    // LDS read offsets: row-major [128][32] tile, 8-elem granules XOR-swizzled
    // by ((row>>1)&3) at write time; read with the same XOR (involution).
    // MFMA tt covers k = tt*16 .. tt*16+15; lane-half kh picks 8 of those.
    const int gsw = (r32 >> 1) & 3;
    int aoff[2][2], boff[NN][2];
    #pragma unroll
    for (int mi = 0; mi < 2; ++mi)
        #pragma unroll
        for (int tt = 0; tt < 2; ++tt)
            aoff[mi][tt] = (wm * 64 + mi * 32 + r32) * 32 +
                           ((tt * 2 + kh) ^ gsw) * 8;
    #pragma unroll
    for (int ni = 0; ni < NN; ++ni)
        #pragma unroll
        for (int tt = 0; tt < 2; ++tt)
            boff[ni][tt] = (wn * (TN / 2) + ni * 32 + r32) * 32 +
                           ((tt * 2 + kh) ^ gsw) * 8;

    auto stage = [&](u16* __restrict__ Ad, u16* __restrict__ Bd) {
        #pragma unroll
        for (int i = 0; i < 2; ++i) {
            __builtin_amdgcn_global_load_lds(
                (const __attribute__((address_space(1))) u32*)pa[i],
                (__attribute__((address_space(3))) u32*)(Ad + (i * 4 + w) * 512),
                16, 0, 0);
            pa[i] += 32;
        }
        #pragma unroll
        for (int i = 0; i < NF / 2; ++i) {
            __builtin_amdgcn_global_load_lds(
                (const __attribute__((address_space(1))) u32*)pb[i],
                (__attribute__((address_space(3))) u32*)(Bd + (i * 4 + w) * 512),
                16, 0, 0);
            pb[i] += 32;
        }
    };
    auto compute = [&](const u16* __restrict__ Ab, const u16* __restrict__ Bb) {
        bf16x8 af[2][2], bfr[NN][2];
        #pragma unroll
        for (int mi = 0; mi < 2; ++mi)
            #pragma unroll
            for (int tt = 0; tt < 2; ++tt)
                af[mi][tt] = *(const bf16x8*)(Ab + aoff[mi][tt]);
        #pragma unroll
        for (int ni = 0; ni < NN; ++ni)
            #pragma unroll
            for (int tt = 0; tt < 2; ++tt)
                bfr[ni][tt] = *(const bf16x8*)(Bb + boff[ni][tt]);
        #pragma unroll
        for (int tt = 0; tt < 2; ++tt)
            #pragma unroll
            for (int mi = 0; mi < 2; ++mi)
                #pragma unroll
                for (int ni = 0; ni < NN; ++ni)
                    acc[mi][ni] = __builtin_amdgcn_mfma_f32_32x32x16_bf16(
                        af[mi][tt], bfr[ni][tt], acc[mi][ni], 0, 0, 0);
    };

    stage(As0, Bs0);
    for (int k0 = 0; k0 < Kloc; k0 += 64) {
        __syncthreads();
        if (k0 + 32 < Kloc) stage(As1, Bs1);
        compute(As0, Bs0);
        __syncthreads();
        if (k0 + 64 < Kloc) stage(As0, Bs0);
        compute(As1, Bs1);
    }

    // C/D layout for 32x32 (HW-verified): col = lane&31,
    // row = (reg&3) + 8*(reg>>2) + 4*(lane>>5), reg in [0,16).
    float* Cfo = (KS == 2 && kz) ? Cf2 : Cf;
    #pragma unroll
    for (int mi = 0; mi < 2; ++mi) {
        #pragma unroll
        for (int ni = 0; ni < NN; ++ni) {
            #pragma unroll
            for (int reg = 0; reg < 16; ++reg) {
                int row = m0 + wm * 64 + mi * 32 + (reg & 3) + 8 * (reg >> 2) + 4 * kh;
                int col = n0 + wn * (TN / 2) + ni * 32 + r32;
                size_t idx = (size_t)row * N + col;
                float v = acc[mi][ni][reg];
                if (EPI == 1) { v += bias[col]; v = (v > 20.f) ? v : log1pf(expf(v)); }
                if (EPI == 2) {
                    v += bias[col];
                    // gelu, tanh form: v * e/(e+1), e = exp(2*0.7978845608*(v+0.044715 v^3))
                    float e = __expf(fminf(1.5957691216f * v + 0.0713548162f * v * v * v, 80.f));
                    v = v * __fdividef(e, e + 1.f);
                }
                if (EPI == 3) { v += resid[idx]; }
                if (EPI == 4) { v += bias[col] + resid[idx]; }
                if (EPI == 2 || EPI == 5) Cb[idx] = f2bf(v);
                else                      Cfo[idx] = v;
            }
        }
    }
}

// ---------------- split-K reduce: out = P0 + P1 + bias + resid -----------
__global__ __launch_bounds__(256) void reduce2_kernel(
        const float* __restrict__ P0, const float* __restrict__ P1,
        const float* __restrict__ bias, const float* __restrict__ resid,
        float* __restrict__ out) {
    size_t idx = ((size_t)blockIdx.x * 256 + threadIdx.x) * 4;
    float4 a = *(const float4*)(P0 + idx);
    float4 b = *(const float4*)(P1 + idx);
    float4 rr = *(const float4*)(resid + idx);
    int col = (int)(idx & (DIMD - 1));
    float4 bb = *(const float4*)(bias + col);
    float4 o;
    o.x = a.x + b.x + rr.x + bb.x;
    o.y = a.y + b.y + rr.y + bb.y;
    o.z = a.z + b.z + rr.z + bb.z;
    o.w = a.w + b.w + rr.w + bb.w;
    *(float4*)(out + idx) = o;
}

// ---------------- fused out_proj reduce + residual + LN2 -----------------
// x2 = P0 + P1 + resid ; ln2_bf = LN(x2)*g + b   (block per row)
__global__ __launch_bounds__(256) void reduce_ln_kernel(
        const float* __restrict__ P0, const float* __restrict__ P1,
        const float* __restrict__ resid,
        const float* __restrict__ g, const float* __restrict__ b,
        float* __restrict__ x2, u16* __restrict__ out_bf) {
    __shared__ float sm[4];
    int row = blockIdx.x;
    int t = threadIdx.x;
    size_t base = (size_t)row * DIMD + t * 4;
    float4 a  = *(const float4*)(P0 + base);
    float4 p  = *(const float4*)(P1 + base);
    float4 rr = *(const float4*)(resid + base);
    float4 v;
    v.x = a.x + p.x + rr.x;
    v.y = a.y + p.y + rr.y;
    v.z = a.z + p.z + rr.z;
    v.w = a.w + p.w + rr.w;
    *(float4*)(x2 + base) = v;
    float s = v.x + v.y + v.z + v.w;
    for (int off = 32; off > 0; off >>= 1) s += __shfl_down(s, off, 64);
    if ((t & 63) == 0) sm[t >> 6] = s;
    __syncthreads();
    float mu = (sm[0] + sm[1] + sm[2] + sm[3]) * (1.0f / DIMD);
    float dx = v.x - mu, dy = v.y - mu, dz = v.z - mu, dw = v.w - mu;
    float ss = dx*dx + dy*dy + dz*dz + dw*dw;
    for (int off = 32; off > 0; off >>= 1) ss += __shfl_down(ss, off, 64);
    __syncthreads();
    if ((t & 63) == 0) sm[t >> 6] = ss;
    __syncthreads();
    float var = (sm[0] + sm[1] + sm[2] + sm[3]) * (1.0f / DIMD);
    float rs = rsqrtf(var + 1e-5f);
    float4 gv = ((const float4*)g)[t];
    float4 bv = ((const float4*)b)[t];
    u16* o = out_bf + base;
    o[0] = f2bf(dx * rs * gv.x + bv.x);
    o[1] = f2bf(dy * rs * gv.y + bv.y);
    o[2] = f2bf(dz * rs * gv.z + bv.z);
    o[3] = f2bf(dw * rs * gv.w + bv.w);
}

// ---------------- depthwise conv + SiLU, sliding window (8 l / thread) ---
__global__ __launch_bounds__(256) void conv_silu_kernel(
        const u16* __restrict__ xz,
        const float* __restrict__ wx, const float* __restrict__ bx,
        const float* __restrict__ wz, const float* __restrict__ bz,
        u16* __restrict__ u_bf, u16* __restrict__ ycat) {
    int c  = blockIdx.x * 256 + threadIdx.x;   // 0..1023
    int gy = blockIdx.y;                       // 0..NTOK/8-1
    int b  = gy >> 8;                          // SEQ/8 = 256 chunks per batch
    int l0 = (gy & 255) * 8;
    const u16* base = xz + ((size_t)(b * SEQ + l0)) * DINNER;
    float wxr[4], wzr[4];
    #pragma unroll
    for (int k = 0; k < 4; ++k) { wxr[k] = wx[c * 4 + k]; wzr[k] = wz[c * 4 + k]; }
    float bxv = bx[c], bzv = bz[c];
    // window: rows l-1, l, l+1 (x and z halves)
    float xm1 = (l0 > 0) ? bf2f(base[c - DINNER]) : 0.f;
    float x0v = bf2f(base[c]);
    float x1v = bf2f(base[c + DINNER]);
    float zm1 = (l0 > 0) ? bf2f(base[HALF + c - DINNER]) : 0.f;
    float z0v = bf2f(base[HALF + c]);
    float z1v = bf2f(base[HALF + c + DINNER]);
    u16* up = u_bf + ((size_t)(b * SEQ + l0)) * HALF + c;
    u16* yp = ycat + ((size_t)(b * SEQ + l0)) * DINNER + HALF + c;
    #pragma unroll
    for (int l = 0; l < 8; ++l) {
        bool in = (l0 + l + 2) < SEQ;
        float x2v = in ? bf2f(base[(size_t)(l + 2) * DINNER + c]) : 0.f;
        float z2v = in ? bf2f(base[(size_t)(l + 2) * DINNER + HALF + c]) : 0.f;
        float ax = bxv + wxr[0]*xm1 + wxr[1]*x0v + wxr[2]*x1v + wxr[3]*x2v;
        float az = bzv + wzr[0]*zm1 + wzr[1]*z0v + wzr[2]*z1v + wzr[3]*z2v;
        float sx = ax * __fdividef(1.f, 1.f + __expf(-ax));
        float sz = az * __fdividef(1.f, 1.f + __expf(-az));
        *up = f2bf(sx); *yp = f2bf(sz);
        up += HALF; yp += DINNER;
        xm1 = x0v; x0v = x1v; x1v = x2v;
        zm1 = z0v; z0v = z1v; z1v = z2v;
    }
}

// ---------------- chunk-parallel selective scan (thread per chain) -------
__global__ __launch_bounds__(256) void scan_p1_kernel(
        const float* __restrict__ delta, const u16* __restrict__ u_bf,
        const float* __restrict__ x_dbl, const float* __restrict__ A_log,
        float* __restrict__ hfin, float* __restrict__ dsum) {
    int t  = blockIdx.x * 256 + threadIdx.x;
    int d  = t & (HALF - 1);
    int ch = (t >> 10) & (NCH - 1);
    int b  = t >> 16;
    float Ac[16], h[16];
    #pragma unroll
    for (int i = 0; i < 4; ++i) {
        float4 a = *(const float4*)&A_log[d * DSTATE + i * 4];
        Ac[4*i+0] = -__expf(a.x); Ac[4*i+1] = -__expf(a.y);
        Ac[4*i+2] = -__expf(a.z); Ac[4*i+3] = -__expf(a.w);
        h[4*i+0] = 0.f; h[4*i+1] = 0.f; h[4*i+2] = 0.f; h[4*i+3] = 0.f;
    }
    int l0 = b * SEQ + ch * CL;
    size_t off = (size_t)l0 * HALF + d;
    const float* xrow = x_dbl + (size_t)l0 * 96;
    float ds = 0.f;
    #pragma unroll 4
    for (int l = 0; l < CL; ++l) {
        float dl = delta[off];
        float uv = bf2f(u_bf[off]);
        off += HALF;
        float4 B0 = *(const float4*)(xrow + 64);
        float4 B1 = *(const float4*)(xrow + 68);
        float4 B2 = *(const float4*)(xrow + 72);
        float4 B3 = *(const float4*)(xrow + 76);
        xrow += 96;
        float dBu = dl * uv;
        ds += dl;
        float Bv[16] = {B0.x,B0.y,B0.z,B0.w, B1.x,B1.y,B1.z,B1.w,
                        B2.x,B2.y,B2.z,B2.w, B3.x,B3.y,B3.z,B3.w};
        #pragma unroll
        for (int n = 0; n < 16; ++n)
            h[n] = __expf(dl * Ac[n]) * h[n] + dBu * Bv[n];
    }
    float4* hf = (float4*)&hfin[(size_t)t * 16];
    #pragma unroll
    for (int i = 0; i < 4; ++i)
        hf[i] = (float4){h[4*i+0], h[4*i+1], h[4*i+2], h[4*i+3]};
    dsum[t] = ds;
}

__global__ __launch_bounds__(256) void scan_p2_kernel(
        const float* __restrict__ A_log, const float* __restrict__ dsum,
        const float* __restrict__ hfin, float* __restrict__ hin) {
    int t = blockIdx.x * 256 + threadIdx.x;
    int n = t & 15;
    int d = (t >> 4) & (HALF - 1);
    int b = t >> 14;
    float Ac = -__expf(A_log[d * DSTATE + n]);
    float h = 0.f;
    for (int ch = 0; ch < NCH; ++ch) {
        size_t chain = ((size_t)(b * NCH + ch) * HALF) + d;
        hin[chain * 16 + n] = h;
        float ds = dsum[chain];
        h = __expf(Ac * ds) * h + hfin[chain * 16 + n];
    }
}

__global__ __launch_bounds__(256) void scan_p3_kernel(
        const float* __restrict__ delta, const u16* __restrict__ u_bf,
        const float* __restrict__ x_dbl, const float* __restrict__ A_log,
        const float* __restrict__ Dp, const float* __restrict__ hin,
        u16* __restrict__ ycat) {
    int t  = blockIdx.x * 256 + threadIdx.x;
    int d  = t & (HALF - 1);
    int ch = (t >> 10) & (NCH - 1);
    int b  = t >> 16;
    float Ac[16], h[16];
    #pragma unroll
    for (int i = 0; i < 4; ++i) {
        float4 a  = *(const float4*)&A_log[d * DSTATE + i * 4];
        float4 hv = *(const float4*)&hin[(size_t)t * 16 + i * 4];
        Ac[4*i+0] = -__expf(a.x); Ac[4*i+1] = -__expf(a.y);
        Ac[4*i+2] = -__expf(a.z); Ac[4*i+3] = -__expf(a.w);
        h[4*i+0] = hv.x; h[4*i+1] = hv.y; h[4*i+2] = hv.z; h[4*i+3] = hv.w;
    }
    float Dv = Dp[d];
    int l0 = b * SEQ + ch * CL;
    size_t off = (size_t)l0 * HALF + d;
    const float* xrow = x_dbl + (size_t)l0 * 96;
    u16* yp = ycat + (size_t)l0 * DINNER + d;
    #pragma unroll 4
    for (int l = 0; l < CL; ++l) {
        float dl = delta[off];
        float uv = bf2f(u_bf[off]);
        off += HALF;
        float4 B0 = *(const float4*)(xrow + 64);
        float4 B1 = *(const float4*)(xrow + 68);
        float4 B2 = *(const float4*)(xrow + 72);
        float4 B3 = *(const float4*)(xrow + 76);
        float4 C0 = *(const float4*)(xrow + 80);
        float4 C1 = *(const float4*)(xrow + 84);
        float4 C2 = *(const float4*)(xrow + 88);
        float4 C3 = *(const float4*)(xrow + 92);
        xrow += 96;
        float dBu = dl * uv;
        float Bv[16] = {B0.x,B0.y,B0.z,B0.w, B1.x,B1.y,B1.z,B1.w,
                        B2.x,B2.y,B2.z,B2.w, B3.x,B3.y,B3.z,B3.w};
        float Cv[16] = {C0.x,C0.y,C0.z,C0.w, C1.x,C1.y,C1.z,C1.w,
                        C2.x,C2.y,C2.z,C2.w, C3.x,C3.y,C3.z,C3.w};
        float y = uv * Dv;
        #pragma unroll
        for (int n = 0; n < 16; ++n) {
            h[n] = __expf(dl * Ac[n]) * h[n] + dBu * Bv[n];
            y += h[n] * Cv[n];
        }
        *yp = f2bf(y);
        yp += DINNER;
    }
}

// ---------------- host-side orchestration ----------------
extern "C" void kernel_launch(void* const* d_in, const int* in_sizes, int n_in,
                              void* d_out, int out_size, void* d_ws, size_t ws_size,
                              hipStream_t stream) {
    const float* x         = (const float*)d_in[0];
    const float* ln1_g     = (const float*)d_in[1];
    const float* ln1_b     = (const float*)d_in[2];
    const float* in_proj_w = (const float*)d_in[3];
    const float* conv_x_w  = (const float*)d_in[4];
    const float* conv_x_b  = (const float*)d_in[5];
    const float* conv_z_w  = (const float*)d_in[6];
    const float* conv_z_b  = (const float*)d_in[7];
    const float* x_proj_w  = (const float*)d_in[8];
    const float* dt_proj_w = (const float*)d_in[9];
    const float* dt_proj_b = (const float*)d_in[10];
    const float* A_log     = (const float*)d_in[11];
    const float* Dp        = (const float*)d_in[12];
    const float* out_proj_w= (const float*)d_in[13];
    const float* ln2_g     = (const float*)d_in[14];
    const float* ln2_b     = (const float*)d_in[15];
    const float* mlp_w1    = (const float*)d_in[16];
    const float* mlp_b1    = (const float*)d_in[17];
    const float* mlp_w2    = (const float*)d_in[18];
    const float* mlp_b2    = (const float*)d_in[19];
    float* out = (float*)d_out;

    char* p = (char*)d_ws;
    auto alloc = [&](size_t bytes) {
        char* r = p; p += (bytes + 255) & ~(size_t)255; return r;
    };
    u16*   w_in   = (u16*)  alloc((size_t)DINNER * DIMD * 2);
    u16*   w_xp   = (u16*)  alloc((size_t)96 * HALF * 2);
    u16*   w_dt   = (u16*)  alloc((size_t)HALF * DTRANK * 2);
    u16*   w_out  = (u16*)  alloc((size_t)DIMD * DINNER * 2);
    u16*   w_m1   = (u16*)  alloc((size_t)MLPD * DIMD * 2);
    u16*   w_m2   = (u16*)  alloc((size_t)DIMD * MLPD * 2);
    u16*   xn_bf  = (u16*)  alloc((size_t)NTOK * DIMD * 2);
    u16*   xz_bf  = (u16*)  alloc((size_t)NTOK * DINNER * 2);  // 16 MB
    u16*   u_bf   = (u16*)  alloc((size_t)NTOK * HALF * 2);
    u16*   ycat   = (u16*)  alloc((size_t)NTOK * DINNER * 2);
    float* x_dbl  = (float*)alloc((size_t)NTOK * 96 * 4);
    u16*   xdbl_bf= (u16*)  alloc((size_t)NTOK * 96 * 2);
    float* delta  = (float*)alloc((size_t)NTOK * HALF * 4);    // 16 MB
    float* x2     = (float*)alloc((size_t)NTOK * DIMD * 4);
    u16*   ln2_bf = (u16*)  alloc((size_t)NTOK * DIMD * 2);
    u16*   mlp_h  = (u16*)  alloc((size_t)NTOK * MLPD * 2);    // 32 MB
    // scan scratch aliases mlp_h (dead until mlp1):
    float* hfin = (float*)mlp_h;
    float* hin  = hfin + (size_t)BSZ * NCH * HALF * DSTATE;
    float* dsum = hin  + (size_t)BSZ * NCH * HALF * DSTATE;
    // split-K partials alias delta (dead after scan) and xz_bf (dead after conv):
    float* P0 = delta;
    float* P1 = (float*)xz_bf;

    // fused LN1 + weight conversions (weights: 4 elems/thread, float4 in, u16x4 out)
    cvtln_kernel<<<NTOK + CVT_BLOCKS, 256, 0, stream>>>(
        x, ln1_g, ln1_b, xn_bf,
        in_proj_w, w_in, x_proj_w, w_xp, dt_proj_w, w_dt,
        out_proj_w, w_out, mlp_w1, w_m1, mlp_w2, w_m2);

    // in_proj: xz_bf[4096,2048] = xn @ W^T (bf16 out, 128x128 tile -> 512 blocks)
    gemm128_kernel<5,128,1><<<dim3(NTOK/128, DINNER/128), 256, 0, stream>>>(
        xn_bf, DIMD, w_in, DIMD, DINNER, nullptr, nullptr, nullptr, nullptr, xz_bf);

    // depthwise conv + silu (sliding window)
    conv_silu_kernel<<<dim3(HALF/256, NTOK/8), 256, 0, stream>>>(
        xz_bf, conv_x_w, conv_x_b, conv_z_w, conv_z_b, u_bf, ycat);

    // x_proj: [4096,96] = u @ W^T  (split-K in block)
    gemm_small_kernel<<<dim3(NTOK/32, 96/16), 256, 0, stream>>>(
        u_bf, HALF, w_xp, HALF, 96, x_dbl, xdbl_bf);

    // dt_proj: delta = softplus(dt @ W^T + b)
    gemm128_kernel<1,64,1><<<dim3(NTOK/128, HALF/64), 256, 0, stream>>>(
        xdbl_bf, 96, w_dt, DTRANK, HALF, dt_proj_b, nullptr, delta, nullptr, nullptr);

    // chunk-parallel scan
    scan_p1_kernel<<<(BSZ*NCH*HALF)/256, 256, 0, stream>>>(
        delta, u_bf, x_dbl, A_log, hfin, dsum);
    scan_p2_kernel<<<(BSZ*HALF*DSTATE)/256, 256, 0, stream>>>(
        A_log, dsum, hfin, hin);
    scan_p3_kernel<<<(BSZ*NCH*HALF)/256, 256, 0, stream>>>(
        delta, u_bf, x_dbl, A_log, Dp, hin, ycat);

    // out_proj split-K=2, 128x128 tile: P = ycat @ W^T (512 blocks = 2/CU)
    gemm128_kernel<0,128,2><<<dim3(NTOK/128, DIMD/128, 2), 256, 0, stream>>>(
        ycat, DINNER, w_out, DINNER, DIMD, nullptr, nullptr, P0, P1, nullptr);
    // fused: x2 = P0+P1+x ; ln2_bf = LN(x2)
    reduce_ln_kernel<<<NTOK, 256, 0, stream>>>(
        P0, P1, x, ln2_g, ln2_b, x2, ln2_bf);

    // MLP1: gelu(ln2 @ W1^T + b1) -> bf16 (overwrites scan scratch - ok)
    gemm128_kernel<2,128,1><<<dim3(NTOK/128, MLPD/128), 256, 0, stream>>>(
        ln2_bf, DIMD, w_m1, DIMD, MLPD, mlp_b1, nullptr, nullptr, nullptr, mlp_h);

    // MLP2 split-K=2, 128x128 tile: P = mlp_h @ W2^T ; out = P0+P1+b2+x2
    gemm128_kernel<0,128,2><<<dim3(NTOK/128, DIMD/128, 2), 256, 0, stream>>>(
        mlp_h, MLPD, w_m2, MLPD, DIMD, nullptr, nullptr, P0, P1, nullptr);
    reduce2_kernel<<<(NTOK*DIMD)/1024, 256, 0, stream>>>(
        P0, P1, mlp_b2, x2, out);
}